// Round 12
// baseline (114.102 us; speedup 1.0000x reference)
//
#include <hip/hip_runtime.h>
#include <math.h>

#define HW   4096
#define CIN  256
#define ICH  128
#define NB   4
#define KSPL 6      // 6 uneven k-splits: grid 32*6*4 = 768 = 3 blocks/CU exactly
#define KVB  32

typedef __attribute__((ext_vector_type(4))) float f32x4;
typedef __attribute__((ext_vector_type(8))) short bf16x8;
typedef __attribute__((ext_vector_type(4))) short bf16x4;
typedef __attribute__((ext_vector_type(4))) unsigned u32x4;

__device__ inline short f2bf(float f) {
    unsigned int u = __float_as_uint(f);
    u += 0x7fffU + ((u >> 16) & 1U);   // round-to-nearest-even
    return (short)(u >> 16);
}

__device__ inline float bf2f(short s) {
    return __uint_as_float(((unsigned int)(unsigned short)s) << 16);
}

__device__ inline float exp2a(float x) {  // 2^x, handles -inf -> 0
    float r;
    asm("v_exp_f32 %0, %1" : "=v"(r) : "v"(x));
    return r;
}
__device__ inline float log2a(float x) {
    float r;
    asm("v_log_f32 %0, %1" : "=v"(r) : "v"(x));
    return r;
}
__device__ inline unsigned cvtpk(float a, float b) {  // lo=bf16(a), hi=bf16(b), RNE
    unsigned r;
    asm("v_cvt_pk_bf16_f32 %0, %1, %2" : "=v"(r) : "v"(a), "v"(b));
    return r;
}

__device__ inline f32x4 mfma16(bf16x8 a, bf16x8 b, f32x4 c) {
    return __builtin_amdgcn_mfma_f32_16x16x32_bf16(a, b, c, 0, 0, 0);
}

__device__ inline bf16x8 ldf(const short* p) { return *(const bf16x8*)p; }

// ---------------------------------------------------------------------------
// K1: x = max_d(feature), cx = feature[:, :, 5]; write (n,q,c) bf16.
// Blocks with blockIdx.y==0 additionally convert the 4 weight matrices to
// bf16 and (block 0) fold the BN params.
// ---------------------------------------------------------------------------
__global__ __launch_bounds__(256) void k_prep_x(const float* __restrict__ feat,
                                                short* __restrict__ Xbf,
                                                short* __restrict__ CXbf,
                                                const float* __restrict__ wth,
                                                const float* __restrict__ wph,
                                                const float* __restrict__ wg,
                                                const float* __restrict__ ww,
                                                const float* __restrict__ gth,
                                                const float* __restrict__ bth,
                                                const float* __restrict__ mth,
                                                const float* __restrict__ vth,
                                                const float* __restrict__ gph,
                                                const float* __restrict__ bph,
                                                const float* __restrict__ mph,
                                                const float* __restrict__ vph,
                                                short* __restrict__ wthb,
                                                short* __restrict__ wphb,
                                                short* __restrict__ wgb,
                                                short* __restrict__ wwb,
                                                float* __restrict__ bnp) {
    const float LOG2E = 1.44269504f;
    const int q0 = blockIdx.x * 64;
    const int c0 = blockIdx.y * 32;
    const int n  = blockIdx.z;
    __shared__ float xs[32][68];
    __shared__ float cxs[32][68];
    const int tid = threadIdx.x;

    // ---- fused weight prep (256 blocks with y==0; 128 elems/matrix each)
    if (blockIdx.y == 0) {
        const int wid = blockIdx.x + 64 * n;       // 0..255
        const int i = wid * 128 + (tid & 127);
        if (tid < 128) {
            wthb[i] = f2bf(wth[i]);
            wphb[i] = f2bf(wph[i]);
        } else {
            wgb[i] = f2bf(wg[i]);
            wwb[i] = f2bf(ww[i]);
        }
        if (wid == 0 && tid < ICH) {
            int o = tid;
            float s1 = gth[o] * rsqrtf(vth[o] + 1e-5f);
            bnp[o]        = s1 * LOG2E;
            bnp[ICH + o]  = (bth[o] - mth[o] * s1) * LOG2E;
            float s2 = gph[o] * rsqrtf(vph[o] + 1e-5f);
            bnp[2*ICH + o] = s2;
            bnp[3*ICH + o] = bph[o] - mph[o] * s2;
        }
    }

    const int qv  = (tid & 15) * 4;
    const int ci  = tid >> 4;          // 0..15

    #pragma unroll
    for (int h = 0; h < 2; ++h) {
        const int cc = h * 16 + ci;
        const float* fp = feat + ((size_t)(n * CIN + c0 + cc)) * 9 * HW + q0 + qv;
        float4 mx = *(const float4*)fp;
        float4 cx = make_float4(0.f, 0.f, 0.f, 0.f);
        #pragma unroll
        for (int d = 1; d < 9; ++d) {
            float4 v = *(const float4*)(fp + (size_t)d * HW);
            if (d == 5) cx = v;
            mx.x = fmaxf(mx.x, v.x); mx.y = fmaxf(mx.y, v.y);
            mx.z = fmaxf(mx.z, v.z); mx.w = fmaxf(mx.w, v.w);
        }
        *(float4*)&xs[cc][qv]  = mx;
        *(float4*)&cxs[cc][qv] = cx;
    }
    __syncthreads();
    #pragma unroll
    for (int it = 0; it < 2; ++it) {
        const int q  = it * 32 + (tid >> 3);
        const int cq = (tid & 7) * 4;
        ushort4 ox, oc;
        ox.x = (unsigned short)f2bf(xs[cq][q]);
        ox.y = (unsigned short)f2bf(xs[cq + 1][q]);
        ox.z = (unsigned short)f2bf(xs[cq + 2][q]);
        ox.w = (unsigned short)f2bf(xs[cq + 3][q]);
        oc.x = (unsigned short)f2bf(cxs[cq][q]);
        oc.y = (unsigned short)f2bf(cxs[cq + 1][q]);
        oc.z = (unsigned short)f2bf(cxs[cq + 2][q]);
        oc.w = (unsigned short)f2bf(cxs[cq + 3][q]);
        const size_t ob = ((size_t)n * HW + q0 + q) * CIN + c0 + cq;
        *(ushort4*)&Xbf[ob]  = ox;
        *(ushort4*)&CXbf[ob] = oc;
    }
}

// ---------------------------------------------------------------------------
// K2: one of {theta, phi, g} per blockIdx.z -> grid (64, 4, 3) = 768 blocks.
// theta/phi (q,c) with BN+ReLU; g with swapped roles -> Vt (c,k).
// ---------------------------------------------------------------------------
__global__ __launch_bounds__(256) void k_conv3(const short* __restrict__ Xbf,
                                               const short* __restrict__ CXbf,
                                               const short* __restrict__ wthb,
                                               const short* __restrict__ wphb,
                                               const short* __restrict__ wgb,
                                               const float* __restrict__ bnp,
                                               short* __restrict__ theta,
                                               short* __restrict__ phi,
                                               short* __restrict__ Vt) {
    const int n    = blockIdx.y;
    const int op   = blockIdx.z;
    const int wave = threadIdx.x >> 6;
    const int lane = threadIdx.x & 63;
    const int lr = lane & 15, lg = lane >> 4;
    const int q0 = blockIdx.x * 64 + wave * 16;
    const short* Xn  = Xbf  + (size_t)n * HW * CIN;
    const short* CXn = CXbf + (size_t)n * HW * CIN;

    f32x4 acc[8];
    #pragma unroll
    for (int i = 0; i < 8; ++i) { acc[i][0]=0.f; acc[i][1]=0.f; acc[i][2]=0.f; acc[i][3]=0.f; }

    if (op == 0) {          // theta = relu(bn(Wth @ cx))
        short* thn = theta + (size_t)n * HW * ICH;
        #pragma unroll
        for (int cf = 0; cf < 8; ++cf) {
            bf16x8 a = ldf(CXn + (q0 + lr) * CIN + cf * 32 + lg * 8);
            #pragma unroll
            for (int of = 0; of < 8; ++of) {
                bf16x8 b = ldf(wthb + (of * 16 + lr) * CIN + cf * 32 + lg * 8);
                acc[of] = mfma16(a, b, acc[of]);
            }
        }
        #pragma unroll
        for (int of = 0; of < 8; ++of) {
            int o = of * 16 + lr;
            float sA = bnp[o], sB = bnp[ICH + o];
            #pragma unroll
            for (int r = 0; r < 4; ++r) {
                int q = q0 + lg * 4 + r;
                thn[q * ICH + o] = f2bf(fmaxf(acc[of][r] * sA + sB, 0.f));
            }
        }
    } else if (op == 1) {   // phi = relu(bn(Wph @ x))
        short* phn = phi + (size_t)n * HW * ICH;
        #pragma unroll
        for (int cf = 0; cf < 8; ++cf) {
            bf16x8 a = ldf(Xn + (q0 + lr) * CIN + cf * 32 + lg * 8);
            #pragma unroll
            for (int of = 0; of < 8; ++of) {
                bf16x8 b = ldf(wphb + (of * 16 + lr) * CIN + cf * 32 + lg * 8);
                acc[of] = mfma16(a, b, acc[of]);
            }
        }
        #pragma unroll
        for (int of = 0; of < 8; ++of) {
            int o = of * 16 + lr;
            float sA = bnp[2*ICH + o], sB = bnp[3*ICH + o];
            #pragma unroll
            for (int r = 0; r < 4; ++r) {
                int q = q0 + lg * 4 + r;
                phn[q * ICH + o] = f2bf(fmaxf(acc[of][r] * sA + sB, 0.f));
            }
        }
    } else {                // g = Wg @ x, swapped MFMA roles -> Vt (c,k)
        short* vtn = Vt + (size_t)n * ICH * HW;
        #pragma unroll
        for (int cf = 0; cf < 8; ++cf) {
            bf16x8 bx = ldf(Xn + (q0 + lr) * CIN + cf * 32 + lg * 8);
            #pragma unroll
            for (int mf = 0; mf < 8; ++mf) {
                bf16x8 a = ldf(wgb + (mf * 16 + lr) * CIN + cf * 32 + lg * 8);
                acc[mf] = mfma16(a, bx, acc[mf]);
            }
        }
        #pragma unroll
        for (int mf = 0; mf < 8; ++mf) {
            #pragma unroll
            for (int r = 0; r < 4; ++r) {
                int o = mf * 16 + lg * 4 + r;
                vtn[(size_t)o * HW + q0 + lr] = f2bf(acc[mf][r]);
            }
        }
    }
}

// ---------------------------------------------------------------------------
// K3: flash attention, k-split x6, swapped QK^T -> lane-local softmax +
// in-register P. Software-pipelined: per iteration
//   {loads(t+1) -> softmax(t) -> LDS writes(t+1) -> barrier -> QK(t+1) -> PV(t)}
// l accumulated on the MFMA pipe via an all-ones A-fragment (lacc); the MFMA
// sums the full K=32 of each tile, so no per-lane partials and no epilogue
// cross-lane reduce. max tree grouped in triples for v_max3 fusion.
// K double-buffered, V TRIPLE-buffered; V read buf for tile t = (vw+2)%3.
// LDS = 2*8K + 3*10.24K = 46.7KB -> 3 blocks/CU; grid 768 = zero tail.
// ---------------------------------------------------------------------------
__global__ __launch_bounds__(256, 3) void k_attn(const short* __restrict__ theta,
                                                 const short* __restrict__ phi,
                                                 const short* __restrict__ Vt,
                                                 short* __restrict__ Op,
                                                 float* __restrict__ Ls) {
    __shared__ char  K_lds[2][8192];        // 32 keys x 128 ch bf16, XOR-swizzled
    __shared__ short V_lds[3][128 * 40];    // 128 ch x 32 keys, stride 40 shorts

    const int bid  = blockIdx.x;
    const int j    = bid & 7;
    const int n    = j >> 1;
    const int rest = ((bid >> 3) << 1) | (j & 1);   // 0..191
    const int qb   = rest / KSPL;                   // 0..31
    const int ks   = rest % KSPL;                   // 0..5
    const int tbase = ks * 21 + (ks < 2 ? ks : 2);  // 0,22,44,65,86,107
    const int tcnt  = 21 + (ks < 2 ? 1 : 0);
    const int tid  = threadIdx.x;
    const int lane = tid & 63;
    const int wave = tid >> 6;
    const int lr = lane & 15, lg = lane >> 4;
    const int q0 = qb * 128 + wave * 32;

    const short* Qn = theta + (size_t)n * HW * ICH;
    const short* Kn = phi   + (size_t)n * HW * ICH;
    const short* Vn = Vt    + (size_t)n * ICH * HW;

    bf16x8 aq[2][4];
    #pragma unroll
    for (int m2 = 0; m2 < 2; ++m2)
        #pragma unroll
        for (int cf = 0; cf < 4; ++cf)
            aq[m2][cf] = ldf(Qn + (q0 + m2 * 16 + lr) * ICH + cf * 32 + lg * 8);

    const short BF1 = (short)0x3F80;   // bf16 1.0
    const bf16x8 vones = { BF1, BF1, BF1, BF1, BF1, BF1, BF1, BF1 };

    // O^T accumulators: O[m2][cc] rows c = cc*16+lg*4+r, col q = q0+m2*16+lr
    f32x4 O[2][8];
    #pragma unroll
    for (int m2 = 0; m2 < 2; ++m2)
        #pragma unroll
        for (int i = 0; i < 8; ++i) { O[m2][i][0]=0.f; O[m2][i][1]=0.f; O[m2][i][2]=0.f; O[m2][i][3]=0.f; }
    f32x4 lacc[2];   // l via ones-MFMA: every reg = sum_k P[k][q=lr]
    lacc[0][0]=0.f; lacc[0][1]=0.f; lacc[0][2]=0.f; lacc[0][3]=0.f;
    lacc[1][0]=0.f; lacc[1][1]=0.f; lacc[1][2]=0.f; lacc[1][3]=0.f;
    float mx[2] = { -INFINITY, -INFINITY };

    f32x4  s[2][2];     // S^T accumulators, live across the iteration boundary
    bf16x8 pb[2];       // P fragments, live across the barrier
    bf16x8 kr0, kr1, vr0, vr1;

    auto loadK = [&](int tabs) {   // linear coalesced b128; swizzle applied on WRITE
        const char* kc = (const char*)(Kn + (size_t)tabs * KVB * ICH);
        kr0 = *(const bf16x8*)(kc + tid * 16);
        kr1 = *(const bf16x8*)(kc + 4096 + tid * 16);
    };
    auto writeK = [&](int pp) {
        const int o0 = tid * 16;
        const int o1 = 4096 + tid * 16;
        *(bf16x8*)&K_lds[pp][o0 ^ (((o0 >> 8) & 7) << 4)] = kr0;
        *(bf16x8*)&K_lds[pp][o1 ^ (((o1 >> 8) & 7) << 4)] = kr1;
    };
    auto loadV = [&](int tabs) {
        vr0 = ldf(Vn + (size_t)(tid >> 2) * HW + tabs * KVB + (tid & 3) * 8);
        vr1 = ldf(Vn + (size_t)((tid + 256) >> 2) * HW + tabs * KVB + (tid & 3) * 8);
    };
    auto writeV = [&](int pp) {
        *(bf16x8*)&V_lds[pp][(tid >> 2) * 40 + (tid & 3) * 8] = vr0;
        *(bf16x8*)&V_lds[pp][((tid + 256) >> 2) * 40 + (tid & 3) * 8] = vr1;
    };
    auto qk = [&](int pp) {        // s = K(buf pp) @ Q^T, 8 ds_read_b128 + 16 MFMA
        #pragma unroll
        for (int tt = 0; tt < 2; ++tt)
            #pragma unroll
            for (int m2 = 0; m2 < 2; ++m2) { s[tt][m2][0]=0.f; s[tt][m2][1]=0.f; s[tt][m2][2]=0.f; s[tt][m2][3]=0.f; }
        __builtin_amdgcn_s_setprio(1);
        #pragma unroll
        for (int tt = 0; tt < 2; ++tt) {
            const int row = tt * 16 + lr;
            const int rsw = (row & 7) << 4;
            #pragma unroll
            for (int cf = 0; cf < 4; ++cf) {
                bf16x8 kf = *(const bf16x8*)(&K_lds[pp][row * 256 + ((cf * 64 + lg * 16) ^ rsw)]);
                s[tt][0] = mfma16(kf, aq[0][cf], s[tt][0]);
                s[tt][1] = mfma16(kf, aq[1][cf], s[tt][1]);
            }
        }
        __builtin_amdgcn_s_setprio(0);
    };
    auto pv = [&](int pp) {        // O += V(buf pp) @ P; l += ones @ P
        __builtin_amdgcn_s_setprio(1);
        #pragma unroll
        for (int cc = 0; cc < 8; ++cc) {
            const short* vb = &V_lds[pp][(cc * 16 + lr) * 40 + lg * 4];
            bf16x4 va0 = *(const bf16x4*)vb;         // keys lg*4 + 0..3
            bf16x4 va1 = *(const bf16x4*)(vb + 16);  // keys 16 + lg*4 + 0..3
            bf16x8 vf = __builtin_shufflevector(va0, va1, 0, 1, 2, 3, 4, 5, 6, 7);
            O[0][cc] = mfma16(vf, pb[0], O[0][cc]);
            O[1][cc] = mfma16(vf, pb[1], O[1][cc]);
        }
        lacc[0] = mfma16(vones, pb[0], lacc[0]);
        lacc[1] = mfma16(vones, pb[1], lacc[1]);
        __builtin_amdgcn_s_setprio(0);
    };

    // prologue: stage tile 0 (Kbuf0, Vbuf0), then QK(0)
    loadK(tbase);
    loadV(tbase);
    writeK(0);
    writeV(0);
    __syncthreads();
    qk(0);

    int vw = 1;   // V write buf for tile t+1; V read buf for tile t = (vw+2)%3
    for (int t = 0; t < tcnt; ++t) {
        const bool pre = (t + 1 < tcnt);
        if (pre) { loadK(tbase + t + 1); loadV(tbase + t + 1); }   // issue-early

        // ---- softmax(t): lane-local, base-2, defer-max THR=11
        float lm[2];
        #pragma unroll
        for (int m2 = 0; m2 < 2; ++m2) {   // triples -> v_max3 fusion
            float t1 = fmaxf(fmaxf(s[0][m2][0], s[0][m2][1]), s[0][m2][2]);
            float t2 = fmaxf(fmaxf(s[0][m2][3], s[1][m2][0]), s[1][m2][1]);
            float t3 = fmaxf(fmaxf(s[1][m2][2], s[1][m2][3]), t1);
            lm[m2] = fmaxf(t2, t3);
        }
        int need = (lm[0] > mx[0] + 11.f) || (lm[1] > mx[1] + 11.f);
        if (__any(need)) {
            #pragma unroll
            for (int m2 = 0; m2 < 2; ++m2) {
                float v = lm[m2];
                v = fmaxf(v, __shfl_xor(v, 16));
                v = fmaxf(v, __shfl_xor(v, 32));
                float mn = fmaxf(mx[m2], v);
                float a  = exp2a(mx[m2] - mn);
                mx[m2] = mn;
                lacc[m2][0] *= a; lacc[m2][1] *= a;
                lacc[m2][2] *= a; lacc[m2][3] *= a;
                #pragma unroll
                for (int cc = 0; cc < 8; ++cc) {
                    O[m2][cc][0] *= a; O[m2][cc][1] *= a;
                    O[m2][cc][2] *= a; O[m2][cc][3] *= a;
                }
            }
        }
        #pragma unroll
        for (int m2 = 0; m2 < 2; ++m2) {
            float e[8];
            #pragma unroll
            for (int r = 0; r < 4; ++r) {
                e[r]     = exp2a(s[0][m2][r] - mx[m2]);
                e[4 + r] = exp2a(s[1][m2][r] - mx[m2]);
            }
            union { u32x4 u; bf16x8 b; } cv;
            cv.u[0] = cvtpk(e[0], e[1]);
            cv.u[1] = cvtpk(e[2], e[3]);
            cv.u[2] = cvtpk(e[4], e[5]);
            cv.u[3] = cvtpk(e[6], e[7]);
            pb[m2] = cv.b;
        }

        if (pre) { writeK((t + 1) & 1); writeV(vw); }   // write-late
        __syncthreads();

        if (pre) qk((t + 1) & 1);       // QK(t+1) issued BEFORE PV(t)
        pv(vw == 0 ? 2 : vw - 1);       // PV(t): read buf = t%3 = (vw+2)%3
        vw = (vw == 2) ? 0 : vw + 1;
    }

    // ---- epilogue: lacc already holds full per-q l (no cross-lane reduce)
    const size_t obase = (size_t)(ks * NB + n) * HW;
    #pragma unroll
    for (int m2 = 0; m2 < 2; ++m2) {
        const float lv = lacc[m2][0];
        const float inv = 1.f / lv;
        const int q = q0 + m2 * 16 + lr;
        #pragma unroll
        for (int cc = 0; cc < 8; ++cc) {
            uint2 ov;
            ov.x = cvtpk(O[m2][cc][0] * inv, O[m2][cc][1] * inv);
            ov.y = cvtpk(O[m2][cc][2] * inv, O[m2][cc][3] * inv);
            *(uint2*)&Op[(obase + q) * ICH + cc * 16 + lg * 4] = ov;
        }
        if (lg == 0)
            Ls[obase + q] = mx[m2] + log2a(lv);
    }
}

// ---------------------------------------------------------------------------
// K4: fused combine + final conv + residual.
// Phase 1: 256 threads cooperatively combine the 6 k-split partials into an
// XOR-swizzled LDS tile. Phase 2: MFMA. grid (128, 4) x 256.
// ---------------------------------------------------------------------------
__global__ __launch_bounds__(256) void k_out(const short* __restrict__ Op,
                                             const float* __restrict__ Ls,
                                             const short* __restrict__ wwb,
                                             const float* __restrict__ feat,
                                             float* __restrict__ out) {
    __shared__ char bo_lds[32 * 256];   // 32 q x 128 c bf16, rows 256B, XOR-swizzled
    const int n   = blockIdx.y;
    const int q0  = blockIdx.x * 32;
    const int tid = threadIdx.x;

    // ---- phase 1: combine splits for (q = tid>>3, c = (tid&7)*16 .. +16)
    {
        const int q  = tid >> 3;
        const int c0 = (tid & 7) * 16;
        const int qg = q0 + q;
        float ls[KSPL], M = -INFINITY;
        #pragma unroll
        for (int i = 0; i < KSPL; ++i) {
            ls[i] = Ls[((size_t)(i * NB + n)) * HW + qg];
            M = fmaxf(M, ls[i]);
        }
        float wq[KSPL], ws = 0.f;
        #pragma unroll
        for (int i = 0; i < KSPL; ++i) { wq[i] = exp2a(ls[i] - M); ws += wq[i]; }
        const float inv = 1.f / ws;
        float fo[16];
        #pragma unroll
        for (int e = 0; e < 16; ++e) fo[e] = 0.f;
        #pragma unroll
        for (int i = 0; i < KSPL; ++i) {
            const short* p = Op + ((size_t)(i * NB + n) * HW + qg) * ICH + c0;
            bf16x8 v0 = ldf(p);
            bf16x8 v1 = ldf(p + 8);
            #pragma unroll
            for (int e = 0; e < 8; ++e) {
                fo[e]     += wq[i] * bf2f(v0[e]);
                fo[8 + e] += wq[i] * bf2f(v1[e]);
            }
        }
        const int rsw = (q & 7) << 4;
        u32x4 w0, w1;
        #pragma unroll
        for (int e = 0; e < 4; ++e) {
            w0[e] = cvtpk(fo[2*e] * inv,     fo[2*e+1] * inv);
            w1[e] = cvtpk(fo[8+2*e] * inv,   fo[8+2*e+1] * inv);
        }
        *(u32x4*)&bo_lds[q * 256 + ((c0 * 2) ^ rsw)]        = w0;
        *(u32x4*)&bo_lds[q * 256 + (((c0 + 8) * 2) ^ rsw)]  = w1;
    }
    __syncthreads();

    // ---- phase 2: out[o, q] = ww @ bO + residual
    const int wave = tid >> 6;
    const int lane = tid & 63;
    const int lr = lane & 15, lg = lane >> 4;
    const int o0 = wave * 64;

    f32x4 acc[4][2];
    #pragma unroll
    for (int i = 0; i < 4; ++i)
        #pragma unroll
        for (int jn = 0; jn < 2; ++jn) { acc[i][jn][0]=0.f; acc[i][jn][1]=0.f; acc[i][jn][2]=0.f; acc[i][jn][3]=0.f; }

    #pragma unroll
    for (int cf = 0; cf < 4; ++cf) {
        bf16x8 bO[2];
        #pragma unroll
        for (int nf = 0; nf < 2; ++nf) {
            const int row = nf * 16 + lr;
            const int byt = (cf * 64 + lg * 16) ^ ((row & 7) << 4);
            bO[nf] = *(const bf16x8*)&bo_lds[row * 256 + byt];
        }
        #pragma unroll
        for (int mf = 0; mf < 4; ++mf) {
            bf16x8 a = ldf(wwb + (o0 + mf * 16 + lr) * ICH + cf * 32 + lg * 8);
            #pragma unroll
            for (int nf = 0; nf < 2; ++nf)
                acc[mf][nf] = mfma16(a, bO[nf], acc[mf][nf]);
        }
    }
    #pragma unroll
    for (int mf = 0; mf < 4; ++mf) {
        #pragma unroll
        for (int nf = 0; nf < 2; ++nf) {
            #pragma unroll
            for (int r = 0; r < 4; ++r) {
                int o = o0 + mf * 16 + lg * 4 + r;
                int q = q0 + nf * 16 + lr;
                long long cxi = (((long long)(n * CIN + o)) * 9 + 5) * HW + q;
                out[((long long)(n * CIN + o)) * HW + q] = acc[mf][nf][r] + feat[cxi];
            }
        }
    }
}

// ---------------------------------------------------------------------------
extern "C" void kernel_launch(void* const* d_in, const int* in_sizes, int n_in,
                              void* d_out, int out_size, void* d_ws, size_t ws_size,
                              hipStream_t stream) {
    const float* feat = (const float*)d_in[0];
    const float* wth  = (const float*)d_in[1];
    const float* gth  = (const float*)d_in[2];
    const float* bth  = (const float*)d_in[3];
    const float* mth  = (const float*)d_in[4];
    const float* vth  = (const float*)d_in[5];
    const float* wph  = (const float*)d_in[6];
    const float* gph  = (const float*)d_in[7];
    const float* bph  = (const float*)d_in[8];
    const float* mph  = (const float*)d_in[9];
    const float* vph  = (const float*)d_in[10];
    const float* wg   = (const float*)d_in[11];
    const float* ww   = (const float*)d_in[12];
    float* out = (float*)d_out;

    size_t off = 0;
    auto carve = [&](size_t bytes) {
        void* p = (char*)d_ws + off;
        off += (bytes + 255) & ~(size_t)255;
        return p;
    };
    short* Xbf   = (short*)carve((size_t)NB * HW * CIN * 2);
    short* CXbf  = (short*)carve((size_t)NB * HW * CIN * 2);
    short* theta = (short*)carve((size_t)NB * HW * ICH * 2);
    short* phi   = (short*)carve((size_t)NB * HW * ICH * 2);
    short* Vt    = (short*)carve((size_t)NB * ICH * HW * 2);
    short* Op    = (short*)carve((size_t)KSPL * NB * HW * ICH * 2);
    float* Ls    = (float*)carve((size_t)KSPL * NB * HW * 4);
    short* wthb  = (short*)carve((size_t)ICH * CIN * 2);
    short* wphb  = (short*)carve((size_t)ICH * CIN * 2);
    short* wgb   = (short*)carve((size_t)ICH * CIN * 2);
    short* wwb   = (short*)carve((size_t)CIN * ICH * 2);
    float* bnp   = (float*)carve((size_t)4 * ICH * 4);

    k_prep_x<<<dim3(64, 8, NB), 256, 0, stream>>>(feat, Xbf, CXbf,
                                                  wth, wph, wg, ww,
                                                  gth, bth, mth, vth,
                                                  gph, bph, mph, vph,
                                                  wthb, wphb, wgb, wwb, bnp);
    k_conv3<<<dim3(64, NB, 3), 256, 0, stream>>>(Xbf, CXbf, wthb, wphb, wgb, bnp,
                                                 theta, phi, Vt);
    k_attn<<<768, 256, 0, stream>>>(theta, phi, Vt, Op, Ls);
    k_out<<<dim3(128, NB), 256, 0, stream>>>(Op, Ls, wwb, feat, out);
}